// Round 17
// baseline (146.392 us; speedup 1.0000x reference)
//
#pragma clang fp contract(off)
#include <hip/hip_runtime.h>
#include <math.h>

#define G       104
#define NBA     9
#define NC      80
#define NBOX    (G*G*NBA)      // 97344
#define CH      (5+NC)         // 85
#define DET_T_  0.02f
#define NMS_T_  0.3f
#define MAXB    50
#define NSEL    (NC*MAXB)      // 4000
#define SORTN   2048
#define IMG     832
#define DB      128            // decode boxes per block
#define BT      1024           // threads per select/draw block
#define RPB     4              // rows per draw block
#define NDRW    ((IMG + RPB - 1) / RPB)   // 208 draw blocks
#define K2BLK   (NC + NDRW)               // 288 blocks in dispatch 2
#define DCHUNK  1024           // draw: selections per chunk
#define RQCAP   (2*DCHUNK)     // run queue cap — worst-case by construction

typedef unsigned long long u64;
typedef unsigned int       u32;
typedef unsigned char      u8;

struct SelLds {
    u64    skey[SORTN];      // 16 KB
    float4 sbox[SORTN];      // 32 KB
    float4 selb[MAXB];
    float  swa[MAXB];
    u64    csA[16], csB[16], sfirst[16];
    int    s_nsel, s_bad, s_cnt;
};
struct DrawLds {
    float   row[RPB * IMG];  // 13.3 KB
    ushort4 runq[RQCAP];     // 16 KB
    int     s_nrun;
};
union K2Lds { SelLds sel; DrawLds dr; };

__device__ __forceinline__ float sigmoidf_(float x) { return 1.0f / (1.0f + expf(-x)); }

// ---------------- decode: dense keys + boxById + clsOf byte map ----------------
// key = score_bits<<24 | (131071-n)<<7 | class; sentinel 0.  clsOf[n] = class or 0xFF.
// All writes unconditional per-slot -> self-initializing.
__global__ __launch_bounds__(DB) void decode_kernel(const float* __restrict__ in,
        const float* __restrict__ anchors, float4* __restrict__ boxById,
        u64* __restrict__ allKey, u8* __restrict__ clsOf)
{
    __shared__ float lds[DB * CH];   // 43,520 B
    const int tid = threadIdx.x;

    const int base = blockIdx.x * (DB * CH);
    int nfl = NBOX * CH - base;
    if (nfl > DB * CH) nfl = DB * CH;

    int nv4 = nfl >> 2;
    const float4* gin4 = (const float4*)(in + base);
    for (int i = tid; i < nv4; i += DB) ((float4*)lds)[i] = gin4[i];
    for (int i = (nv4 << 2) + tid; i < nfl; i += DB) lds[i] = in[base + i];
    __syncthreads();

    int n = blockIdx.x * DB + tid;
    if (n >= NBOX) return;
    const float* p = lds + tid * CH;

    float m = -INFINITY;
#pragma unroll
    for (int i = 0; i < NC; ++i) m = fmaxf(m, p[5 + i]);

    // sum in reference order + candidate bitmask (window -2e-6, 5x margin)
    float sum = 0.0f;
    u64 cm0 = 0, cm1 = 0;
#pragma unroll
    for (int i = 0; i < NC; ++i) {
        float d = p[5 + i] - m;
        sum += expf(d);
        u64 cand = (d >= -2.0e-6f) ? 1ull : 0ull;
        if (i < 64) cm0 |= cand << i;
        else        cm1 |= cand << (i - 64);
    }
    float obj = sigmoidf_(p[4]);

    // exact first-max over candidate classes only (ascending index)
    float best = -1.0f; int bcls = 0;
    while (cm0) {
        int i = __ffsll((long long)cm0) - 1; cm0 &= cm0 - 1;
        float e = expf(p[5 + i] - m);
        float s = obj * (e / sum);
        if (s > best) { best = s; bcls = i; }
    }
    while (cm1) {
        int i = __ffsll((long long)cm1) - 1 + 64; cm1 &= cm1 - 1;
        float e = expf(p[5 + i] - m);
        float s = obj * (e / sum);
        if (s > best) { best = s; bcls = i; }
    }

    u64 key = 0; u8 cls = 0xFF;
    if (best > DET_T_) {
        int a  = n % NBA;
        int t2 = n / NBA;
        int gx = t2 % G;
        int gy = t2 / G;
        float bx = (sigmoidf_(p[0]) + (float)gx) / (float)G;
        float by = (sigmoidf_(p[1]) + (float)gy) / (float)G;
        float bw = expf(p[2]) * anchors[2*a + 0] / (float)G;
        float bh = expf(p[3]) * anchors[2*a + 1] / (float)G;
        boxById[n] = make_float4(bx - bw / 2.0f, by - bh / 2.0f,
                                 bx + bw / 2.0f, by + bh / 2.0f);
        key = ((u64)__float_as_uint(best) << 24) | ((u64)(131071 - n) << 7) | (u64)bcls;
        cls = (u8)bcls;
    }
    allKey[n] = key;
    clsOf[n]  = cls;
}

// ---------------- helpers ----------------
__device__ __forceinline__ int to_px(float v) {
    float r = rintf(v * 831.0f);           // jnp.round = half-to-even
    r = fminf(fmaxf(r, 0.0f), 831.0f);     // clip AFTER round
    return (int)r;
}

// reference-exact IoU(winner W area aW, candidate C area aC) > T
__device__ __forceinline__ bool iou_gt_pre(const float4 W, float aW,
                                           const float4 C, float aC) {
    float x1 = fmaxf(W.x, C.x), y1 = fmaxf(W.y, C.y);
    float x2 = fminf(W.z, C.z), y2 = fminf(W.w, C.w);
    float inter = fmaxf(x2 - x1, 0.0f) * fmaxf(y2 - y1, 0.0f);
    float uni = aW + aC - inter;
    float iou = (uni > 0.0f) ? (inter / uni) : 0.0f;
    return iou > NMS_T_;
}

// bitonic compare-exchange via shfl_xor (stride <= 32), element index x
__device__ __forceinline__ u64 cex_shfl(u64 r, int x, int stride, int size) {
    u64 v = __shfl_xor(r, stride);
    bool asc   = (x & size) != 0;
    bool upper = (x & stride) != 0;
    bool keep_max = (!asc) != upper;     // XOR
    u64 mx = (r > v) ? r : v;
    u64 mn = (r > v) ? v : r;
    return keep_max ? mx : mn;
}

// ---------------- dispatch 2: blocks 0..79 select, blocks 80..287 draw ----------------
__global__ __launch_bounds__(BT) void select_draw_kernel(
    const float4* __restrict__ boxById, const u64* __restrict__ allKey,
    const u8* __restrict__ clsOf, ushort4* __restrict__ selPx,
    float* __restrict__ out, int* __restrict__ done)
{
    __shared__ K2Lds u;
    const int b = blockIdx.x;
    const int t = threadIdx.x;

    if (b < NC) {
        // ================= SELECT (R14-proven body; clsOf-based filter) =========
        u64*    skey = u.sel.skey;
        float4* sbox = u.sel.sbox;
        float4* selb = u.sel.selb;
        float*  swa  = u.sel.swa;
        const int c = b;
        const int w = t >> 6, l = t & 63;
        const int eA = (w << 7) + l, eB = eA + 64;

        if (t == 0) { u.sel.s_bad = 0; u.sel.s_nsel = 0; u.sel.s_cnt = 0; }
        for (int i = t; i < SORTN; i += BT) skey[i] = 0;
        __syncthreads();

        // filter via clsOf byte map — EXACT carry-free per-byte zero detect:
        // bit7 of each byte of zb is set iff that byte of x is exactly 0
        // (masked add 0x7F+0x7F=0xFE cannot carry across byte boundaries;
        //  R16's (x-0x01010101)&~x&0x80808080 had borrow false-positives)
        {
            const uint4* cls4 = (const uint4*)clsOf;
            const u32 cpat = (u32)c * 0x01010101u;
            for (int pi = t; pi < NBOX/16; pi += BT) {
                uint4 cw = cls4[pi];
                u32 words[4] = { cw.x, cw.y, cw.z, cw.w };
#pragma unroll
                for (int q = 0; q < 4; ++q) {
                    u32 x  = words[q] ^ cpat;
                    u32 zb = ~((((x & 0x7F7F7F7Fu) + 0x7F7F7F7Fu) | x) | 0x7F7F7F7Fu);
                    while (zb) {
                        int byte = (__ffs(zb) - 1) >> 3;
                        int n = pi * 16 + q * 4 + byte;
                        int pos = atomicAdd(&u.sel.s_cnt, 1);
                        if (pos < SORTN) skey[pos] = allKey[n];
                        zb &= zb - 1;
                    }
                }
            }
        }
        __syncthreads();
        int count = u.sel.s_cnt; if (count > SORTN) count = SORTN;

        u64 rA = skey[eA];
        u64 rB = skey[eB];

        // checksum of input multiset (XOR order-independent)
        {
            u64 x = rA ^ rB;
#pragma unroll
            for (int off = 32; off >= 1; off >>= 1) x ^= __shfl_xor(x, off);
            if (l == 0) u.sel.csA[w] = x;
        }

        // Phase A: in-register bitonic sort of each 128-chunk (no barriers)
#pragma unroll
        for (int size = 2; size <= 64; size <<= 1)
            for (int stride = size >> 1; stride >= 1; stride >>= 1) {
                rA = cex_shfl(rA, eA, stride, size);
                rB = cex_shfl(rB, eB, stride, size);
            }
        {   const int size = 128;
            bool asc = (eA & 128) != 0;
            u64 mx = (rA > rB) ? rA : rB, mn = (rA > rB) ? rB : rA;
            rA = asc ? mn : mx; rB = asc ? mx : mn;
            for (int stride = 32; stride >= 1; stride >>= 1) {
                rA = cex_shfl(rA, eA, stride, size);
                rB = cex_shfl(rB, eB, stride, size);
            }
        }

        // Phase B: merge sizes 256..2048; only stride>=128 passes touch LDS
        for (int size = 256; size <= 2048; size <<= 1) {
            skey[eA] = rA; skey[eB] = rB;
            __syncthreads();
            for (int stride = size >> 1; stride >= 128; stride >>= 1) {
                int i = ((t & ~(stride - 1)) << 1) | (t & (stride - 1));
                int j = i | stride;
                bool asc = (i & size) != 0;
                u64 ki = skey[i], kj = skey[j];
                bool sw = asc ? (ki > kj) : (ki < kj);
                if (sw) { skey[i] = kj; skey[j] = ki; }
                __syncthreads();
            }
            rA = skey[eA]; rB = skey[eB];
            bool asc = (eA & size) != 0;
            u64 mx = (rA > rB) ? rA : rB, mn = (rA > rB) ? rB : rA;
            rA = asc ? mn : mx; rB = asc ? mx : mn;
            for (int stride = 32; stride >= 1; stride >>= 1) {
                rA = cex_shfl(rA, eA, stride, size);
                rB = cex_shfl(rB, eB, stride, size);
            }
        }

        // verify: descending order + XOR checksum
        {
            u64 x = rA ^ rB;
#pragma unroll
            for (int off = 32; off >= 1; off >>= 1) x ^= __shfl_xor(x, off);
            if (l == 0) { u.sel.csB[w] = x; u.sel.sfirst[w] = rA; }
            bool bad = false;
            u64 dA  = __shfl_down(rA, 1);
            u64 dB  = __shfl_down(rB, 1);
            u64 rB0 = __shfl(rB, 0);
            if (l < 63) { bad |= (rA < dA); bad |= (rB < dB); }
            if (l == 63) bad |= (rA < rB0);
            __syncthreads();
            if (l == 63 && w < 15) bad |= (rB < u.sel.sfirst[w + 1]);
            if (t == 0) {
                u64 X0 = 0, X1 = 0;
                for (int i = 0; i < 16; ++i) { X0 ^= u.sel.csA[i]; X1 ^= u.sel.csB[i]; }
                if (X0 != X1) u.sel.s_bad = 1;
            }
            if (bad) u.sel.s_bad = 1;
            __syncthreads();
        }

        if (u.sel.s_bad) {   // dormant fallback: exact re-filter + odd-even transposition
            for (int i = t; i < SORTN; i += BT) skey[i] = 0;
            if (t == 0) u.sel.s_cnt = 0;
            __syncthreads();
            for (int i = t; i < NBOX; i += BT) {
                if (clsOf[i] == (u8)c) {
                    int pos = atomicAdd(&u.sel.s_cnt, 1);
                    if (pos < SORTN) skey[pos] = allKey[i];
                }
            }
            __syncthreads();
            for (int ph = 0; ph < SORTN; ++ph) {
                int i = (t << 1) + (ph & 1);
                if (i + 1 < SORTN) {
                    u64 a = skey[i], bb = skey[i + 1];
                    if (a < bb) { skey[i] = bb; skey[i + 1] = a; }
                }
                __syncthreads();
            }
            rA = skey[eA]; rB = skey[eB];
        }

        // gather boxes into sorted order (id = 131071 - key[23:7])
        if (eA < count) sbox[eA] = boxById[131071 - (int)((rA >> 7) & 0x1FFFF)];
        if (eB < count) sbox[eB] = boxById[131071 - (int)((rB >> 7) & 0x1FFFF)];
        __syncthreads();

        // wave-0 batched walk (exact sorted-greedy == reference argmax NMS)
        if (t < 64) {
            const int lane = t;
            int nsel = 0;
            for (int p0 = 0; p0 < count && nsel < MAXB; p0 += 64) {
                int p = p0 + lane;
                bool have = (p < count);
                float4 C = sbox[have ? p : 0];
                float aC = (C.z - C.x) * (C.w - C.y);

                bool sup = false;
#pragma unroll 4
                for (int ww = 0; ww < nsel; ++ww)
                    sup |= iou_gt_pre(selb[ww], swa[ww], C, aC);

                u64 alive = __ballot(have && !sup);
                while (alive != 0ull && nsel < MAXB) {
                    int i = __ffsll((long long)alive) - 1;
                    float4 Wn = make_float4(__shfl(C.x, i), __shfl(C.y, i),
                                            __shfl(C.z, i), __shfl(C.w, i));
                    float aWn = __shfl(aC, i);
                    if (lane == 0) { selb[nsel] = Wn; swa[nsel] = aWn; }
                    ++nsel;
                    u64 killed = __ballot(have && iou_gt_pre(Wn, aWn, C, aC));
                    alive &= ~killed;
                }
            }
            if (lane == 0) u.sel.s_nsel = nsel;
        }
        __syncthreads();

        // emit pixel coords; sentinel 0xFFFF (unconditional = self-init)
        int nsel = u.sel.s_nsel;
        for (int k = t; k < MAXB; k += BT) {
            ushort4 px = make_ushort4(0xFFFF, 0xFFFF, 0xFFFF, 0xFFFF);
            if (k < nsel) {
                float4 B = selb[k];
                px = make_ushort4((unsigned short)to_px(B.x), (unsigned short)to_px(B.y),
                                  (unsigned short)to_px(B.z), (unsigned short)to_px(B.w));
            }
            selPx[c*MAXB + k] = px;
        }

        // release: every thread fences its own stores, barrier, then one atomic
        __threadfence();
        __syncthreads();
        if (t == 0) atomicAdd(done, 1);
    } else {
        // ================= DRAW (R14-proven row rasterizer + spin barrier) ======
        const int wv = t >> 6, ln = t & 63;
        const int r0 = (b - NC) * RPB;

        for (int i = t; i < RPB * IMG; i += BT) u.dr.row[i] = 0.0f;  // overlap with spin

        // acquire: spin until all NC selects released, then fence
        if (t == 0) {
            while (atomicAdd(done, 0) < NC) __builtin_amdgcn_s_sleep(32);
        }
        __syncthreads();
        __threadfence();

        for (int cb = 0; cb < NSEL; cb += DCHUNK) {
            if (t == 0) u.dr.s_nrun = 0;
            __syncthreads();

            int cend = cb + DCHUNK; if (cend > NSEL) cend = NSEL;
            for (int bb = cb + t; bb < cend; bb += BT) {
                ushort4 B = selPx[bb];
                if (B.x == 0xFFFF) continue;
                int r1 = B.x, c1 = B.y, r2 = B.z, c2 = B.w;
#pragma unroll
                for (int rl = 0; rl < RPB; ++rl) {
                    int r = r0 + rl;
                    if (r >= r1 && r <= r2) {
                        u.dr.row[rl*IMG + c1] = 1.0f;   // vertical edges (races benign)
                        u.dr.row[rl*IMG + c2] = 1.0f;
                        if (r == r1 || r == r2) {
                            int qi = atomicAdd(&u.dr.s_nrun, 1);
                            u.dr.runq[qi] = make_ushort4((unsigned short)rl, B.y, B.w, 0);
                            // qi < RQCAP guaranteed: <=2 runs/box, DCHUNK boxes/chunk
                        }
                    }
                }
            }
            __syncthreads();

            int nrun = u.dr.s_nrun;
            for (int q = wv; q < nrun; q += 16) {
                ushort4 R = u.dr.runq[q];
                int base = (int)R.x * IMG;
                for (int i = (int)R.y + ln; i <= (int)R.z; i += 64) u.dr.row[base + i] = 1.0f;
            }
            __syncthreads();
        }

        // coalesced write (every pixel written -> self-init canvas)
        float4* o4 = (float4*)(out + r0 * IMG);
        for (int i = t; i < RPB * IMG / 4; i += BT)
            o4[i] = make_float4(u.dr.row[4*i], u.dr.row[4*i+1],
                                u.dr.row[4*i+2], u.dr.row[4*i+3]);
    }
}

extern "C" void kernel_launch(void* const* d_in, const int* in_sizes, int n_in,
                              void* d_out, int out_size, void* d_ws, size_t ws_size,
                              hipStream_t stream)
{
    const float* in      = (const float*)d_in[0];
    const float* anchors = (const float*)d_in[1];
    float* out           = (float*)d_out;

    char* ws = (char*)d_ws;
    size_t off = 0;
    float4*  boxById = (float4*)(ws + off);  off += (size_t)NBOX * sizeof(float4);   // 1,557,504
    u64*     allKey  = (u64*)(ws + off);     off += (size_t)NBOX * sizeof(u64);      //   778,752
    ushort4* selPx   = (ushort4*)(ws + off); off += (size_t)NSEL * sizeof(ushort4);  //    32,000
    u8*      clsOf   = (u8*)(ws + off);      off += (size_t)NBOX;                    //    97,344
    off = (off + 15) & ~(size_t)15;
    int*     done    = (int*)(ws + off);     off += 16;

    hipMemsetAsync(done, 0, sizeof(int), stream);   // init at the coherent point
    decode_kernel<<<(NBOX + DB - 1)/DB, DB, 0, stream>>>(in, anchors, boxById, allKey, clsOf);
    select_draw_kernel<<<K2BLK, BT, 0, stream>>>(boxById, allKey, clsOf, selPx, out, done);
}

// Round 18
// 75.047 us; speedup vs baseline: 1.9507x; 1.9507x over previous
//
#pragma clang fp contract(off)
#include <hip/hip_runtime.h>
#include <math.h>

#define G       104
#define NBA     9
#define NC      80
#define NBOX    (G*G*NBA)      // 97344
#define CH      (5+NC)         // 85
#define DET_T_  0.02f
#define NMS_T_  0.3f
#define MAXB    50
#define SORTN   2048
#define IMG     832
#define DB      128            // decode boxes per block

typedef unsigned long long u64;
typedef unsigned int       u32;
typedef unsigned char      u8;

__device__ __forceinline__ float sigmoidf_(float x) { return 1.0f / (1.0f + expf(-x)); }

// ---------------- decode: dense keys + boxById + clsOf + canvas zero ----------------
// key = score_bits<<24 | (131071-n)<<7 | class; sentinel 0.  clsOf[n] = class or 0xFF.
// All writes unconditional per-slot -> self-initializing.
__global__ __launch_bounds__(DB) void decode_kernel(const float* __restrict__ in,
        const float* __restrict__ anchors, float4* __restrict__ boxById,
        u64* __restrict__ allKey, u8* __restrict__ clsOf, float4* __restrict__ out4)
{
    __shared__ float lds[DB * CH];   // 43,520 B
    const int tid = threadIdx.x;

    // canvas zero slice (stream-ordered before select_draw)
    {
        const int CZ = (IMG*IMG/4 + 760) / 761;   // 228 float4 per block
        int zbase = blockIdx.x * CZ;
        for (int i = tid; i < CZ; i += DB) {
            int idx = zbase + i;
            if (idx < IMG*IMG/4) out4[idx] = make_float4(0, 0, 0, 0);
        }
    }

    const int base = blockIdx.x * (DB * CH);
    int nfl = NBOX * CH - base;
    if (nfl > DB * CH) nfl = DB * CH;

    int nv4 = nfl >> 2;
    const float4* gin4 = (const float4*)(in + base);
    for (int i = tid; i < nv4; i += DB) ((float4*)lds)[i] = gin4[i];
    for (int i = (nv4 << 2) + tid; i < nfl; i += DB) lds[i] = in[base + i];
    __syncthreads();

    int n = blockIdx.x * DB + tid;
    if (n >= NBOX) return;
    const float* p = lds + tid * CH;

    float m = -INFINITY;
#pragma unroll
    for (int i = 0; i < NC; ++i) m = fmaxf(m, p[5 + i]);

    // sum in reference order + candidate bitmask (window -2e-6, 5x margin)
    float sum = 0.0f;
    u64 cm0 = 0, cm1 = 0;
#pragma unroll
    for (int i = 0; i < NC; ++i) {
        float d = p[5 + i] - m;
        sum += expf(d);
        u64 cand = (d >= -2.0e-6f) ? 1ull : 0ull;
        if (i < 64) cm0 |= cand << i;
        else        cm1 |= cand << (i - 64);
    }
    float obj = sigmoidf_(p[4]);

    // exact first-max over candidate classes only (ascending index)
    float best = -1.0f; int bcls = 0;
    while (cm0) {
        int i = __ffsll((long long)cm0) - 1; cm0 &= cm0 - 1;
        float e = expf(p[5 + i] - m);
        float s = obj * (e / sum);
        if (s > best) { best = s; bcls = i; }
    }
    while (cm1) {
        int i = __ffsll((long long)cm1) - 1 + 64; cm1 &= cm1 - 1;
        float e = expf(p[5 + i] - m);
        float s = obj * (e / sum);
        if (s > best) { best = s; bcls = i; }
    }

    u64 key = 0; u8 cls = 0xFF;
    if (best > DET_T_) {
        int a  = n % NBA;
        int t2 = n / NBA;
        int gx = t2 % G;
        int gy = t2 / G;
        float bx = (sigmoidf_(p[0]) + (float)gx) / (float)G;
        float by = (sigmoidf_(p[1]) + (float)gy) / (float)G;
        float bw = expf(p[2]) * anchors[2*a + 0] / (float)G;
        float bh = expf(p[3]) * anchors[2*a + 1] / (float)G;
        boxById[n] = make_float4(bx - bw / 2.0f, by - bh / 2.0f,
                                 bx + bw / 2.0f, by + bh / 2.0f);
        key = ((u64)__float_as_uint(best) << 24) | ((u64)(131071 - n) << 7) | (u64)bcls;
        cls = (u8)bcls;
    }
    allKey[n] = key;
    clsOf[n]  = cls;
}

// ---------------- helpers ----------------
__device__ __forceinline__ int to_px(float v) {
    float r = rintf(v * 831.0f);           // jnp.round = half-to-even
    r = fminf(fmaxf(r, 0.0f), 831.0f);     // clip AFTER round
    return (int)r;
}

// reference-exact IoU(winner W area aW, candidate C area aC) > T
__device__ __forceinline__ bool iou_gt_pre(const float4 W, float aW,
                                           const float4 C, float aC) {
    float x1 = fmaxf(W.x, C.x), y1 = fmaxf(W.y, C.y);
    float x2 = fminf(W.z, C.z), y2 = fminf(W.w, C.w);
    float inter = fmaxf(x2 - x1, 0.0f) * fmaxf(y2 - y1, 0.0f);
    float uni = aW + aC - inter;
    float iou = (uni > 0.0f) ? (inter / uni) : 0.0f;
    return iou > NMS_T_;
}

// bitonic compare-exchange via shfl_xor (stride <= 32), element index x
__device__ __forceinline__ u64 cex_shfl(u64 r, int x, int stride, int size) {
    u64 v = __shfl_xor(r, stride);
    bool asc   = (x & size) != 0;
    bool upper = (x & stride) != 0;
    bool keep_max = (!asc) != upper;     // XOR
    u64 mx = (r > v) ? r : v;
    u64 mn = (r > v) ? v : r;
    return keep_max ? mx : mn;
}

// ---------------- per-class: clsOf filter -> hybrid sort -> walk -> scatter draw ----------------
__global__ __launch_bounds__(1024) void select_draw_kernel(
    const float4* __restrict__ boxById, const u64* __restrict__ allKey,
    const u8* __restrict__ clsOf, float* __restrict__ out)
{
    __shared__ u64    skey[SORTN];    // 16 KB
    __shared__ float4 sbox[SORTN];    // 32 KB
    __shared__ float4 selb[MAXB];
    __shared__ float  swa[MAXB];      // winner areas
    __shared__ u64    csA[16], csB[16], sfirst[16];
    __shared__ int    s_nsel, s_bad, s_cnt;

    const int c = blockIdx.x;
    const int t = threadIdx.x;
    const int w = t >> 6, l = t & 63;
    const int eA = (w << 7) + l, eB = eA + 64;   // wave w owns elements [128w,128w+128)

    if (t == 0) { s_bad = 0; s_nsel = 0; s_cnt = 0; }
    for (int i = t; i < SORTN; i += 1024) skey[i] = 0;
    __syncthreads();

    // ---- filter via clsOf byte map — EXACT carry-free per-byte zero detect
    // (R17-proven: masked add 0x7F+0x7F cannot carry across byte boundaries)
    {
        const uint4* cls4 = (const uint4*)clsOf;
        const u32 cpat = (u32)c * 0x01010101u;
        for (int pi = t; pi < NBOX/16; pi += 1024) {
            uint4 cw = cls4[pi];
            u32 words[4] = { cw.x, cw.y, cw.z, cw.w };
#pragma unroll
            for (int q = 0; q < 4; ++q) {
                u32 x  = words[q] ^ cpat;
                u32 zb = ~((((x & 0x7F7F7F7Fu) + 0x7F7F7F7Fu) | x) | 0x7F7F7F7Fu);
                while (zb) {
                    int byte = (__ffs(zb) - 1) >> 3;
                    int n = pi * 16 + q * 4 + byte;
                    int pos = atomicAdd(&s_cnt, 1);
                    if (pos < SORTN) skey[pos] = allKey[n];
                    zb &= zb - 1;
                }
            }
        }
    }
    __syncthreads();
    int count = s_cnt; if (count > SORTN) count = SORTN;

    u64 rA = skey[eA];
    u64 rB = skey[eB];

    // checksum of input multiset (XOR order-independent)
    {
        u64 x = rA ^ rB;
#pragma unroll
        for (int off = 32; off >= 1; off >>= 1) x ^= __shfl_xor(x, off);
        if (l == 0) csA[w] = x;
    }

    // ---- Phase A: in-register bitonic sort of each 128-chunk (no barriers) ----
#pragma unroll
    for (int size = 2; size <= 64; size <<= 1)
        for (int stride = size >> 1; stride >= 1; stride >>= 1) {
            rA = cex_shfl(rA, eA, stride, size);
            rB = cex_shfl(rB, eB, stride, size);
        }
    {   // size = 128: stride 64 is the in-lane register pair
        const int size = 128;
        bool asc = (eA & 128) != 0;
        u64 mx = (rA > rB) ? rA : rB, mn = (rA > rB) ? rB : rA;
        rA = asc ? mn : mx; rB = asc ? mx : mn;
        for (int stride = 32; stride >= 1; stride >>= 1) {
            rA = cex_shfl(rA, eA, stride, size);
            rB = cex_shfl(rB, eB, stride, size);
        }
    }

    // ---- Phase B: merge sizes 256..2048; only stride>=128 passes touch LDS ----
    for (int size = 256; size <= 2048; size <<= 1) {
        skey[eA] = rA; skey[eB] = rB;
        __syncthreads();
        for (int stride = size >> 1; stride >= 128; stride >>= 1) {
            int i = ((t & ~(stride - 1)) << 1) | (t & (stride - 1));
            int j = i | stride;
            bool asc = (i & size) != 0;
            u64 ki = skey[i], kj = skey[j];
            bool sw = asc ? (ki > kj) : (ki < kj);
            if (sw) { skey[i] = kj; skey[j] = ki; }
            __syncthreads();
        }
        rA = skey[eA]; rB = skey[eB];
        bool asc = (eA & size) != 0;   // stride 64: in-lane pair
        u64 mx = (rA > rB) ? rA : rB, mn = (rA > rB) ? rB : rA;
        rA = asc ? mn : mx; rB = asc ? mx : mn;
        for (int stride = 32; stride >= 1; stride >>= 1) {
            rA = cex_shfl(rA, eA, stride, size);
            rB = cex_shfl(rB, eB, stride, size);
        }
    }

    // ---- verify: descending order + XOR checksum ----
    {
        u64 x = rA ^ rB;
#pragma unroll
        for (int off = 32; off >= 1; off >>= 1) x ^= __shfl_xor(x, off);
        if (l == 0) { csB[w] = x; sfirst[w] = rA; }
        bool bad = false;
        u64 dA  = __shfl_down(rA, 1);
        u64 dB  = __shfl_down(rB, 1);
        u64 rB0 = __shfl(rB, 0);
        if (l < 63) { bad |= (rA < dA); bad |= (rB < dB); }
        if (l == 63) bad |= (rA < rB0);
        __syncthreads();
        if (l == 63 && w < 15) bad |= (rB < sfirst[w + 1]);
        if (t == 0) {
            u64 X0 = 0, X1 = 0;
            for (int i = 0; i < 16; ++i) { X0 ^= csA[i]; X1 ^= csB[i]; }
            if (X0 != X1) s_bad = 1;
        }
        if (bad) s_bad = 1;
        __syncthreads();
    }

    if (s_bad) {   // dormant fallback: exact re-filter + odd-even transposition
        for (int i = t; i < SORTN; i += 1024) skey[i] = 0;
        if (t == 0) s_cnt = 0;
        __syncthreads();
        for (int i = t; i < NBOX; i += 1024) {
            if (clsOf[i] == (u8)c) {
                int pos = atomicAdd(&s_cnt, 1);
                if (pos < SORTN) skey[pos] = allKey[i];
            }
        }
        __syncthreads();
        for (int ph = 0; ph < SORTN; ++ph) {
            int i = (t << 1) + (ph & 1);
            if (i + 1 < SORTN) {
                u64 a = skey[i], b = skey[i + 1];
                if (a < b) { skey[i] = b; skey[i + 1] = a; }
            }
            __syncthreads();
        }
        rA = skey[eA]; rB = skey[eB];
    }

    // ---- gather boxes into sorted order (id = 131071 - key[23:7]) ----
    if (eA < count) sbox[eA] = boxById[131071 - (int)((rA >> 7) & 0x1FFFF)];
    if (eB < count) sbox[eB] = boxById[131071 - (int)((rB >> 7) & 0x1FFFF)];
    __syncthreads();

    // ---- wave-0 batched walk (exact sorted-greedy == reference argmax NMS) ----
    if (t < 64) {
        const int lane = t;
        int nsel = 0;
        for (int p0 = 0; p0 < count && nsel < MAXB; p0 += 64) {
            int p = p0 + lane;
            bool have = (p < count);
            float4 C = sbox[have ? p : 0];
            float aC = (C.z - C.x) * (C.w - C.y);   // hoisted, bit-exact

            // NO early exit: iterations independent -> LDS loads pipeline
            bool sup = false;
#pragma unroll 4
            for (int ww = 0; ww < nsel; ++ww)
                sup |= iou_gt_pre(selb[ww], swa[ww], C, aC);

            u64 alive = __ballot(have && !sup);
            while (alive != 0ull && nsel < MAXB) {
                int i = __ffsll((long long)alive) - 1;   // lowest sorted index first
                float4 Wn = make_float4(__shfl(C.x, i), __shfl(C.y, i),
                                        __shfl(C.z, i), __shfl(C.w, i));
                float aWn = __shfl(aC, i);
                if (lane == 0) { selb[nsel] = Wn; swa[nsel] = aWn; }  // same-wave RAW ordered
                ++nsel;
                u64 killed = __ballot(have && iou_gt_pre(Wn, aWn, C, aC)); // self-IoU=1 kills i
                alive &= ~killed;
            }
        }
        if (lane == 0) s_nsel = nsel;
    }
    __syncthreads();

    // ---- cooperative scatter draw across all 16 waves (1.0f races benign) ----
    int nsel = s_nsel;
    int lane = t & 63;
    for (int b = t >> 6; b < nsel; b += 16) {
        float4 B = selb[b];
        int r1 = to_px(B.x), c1 = to_px(B.y), r2 = to_px(B.z), c2 = to_px(B.w);
        for (int i = c1 + lane; i <= c2; i += 64) {
            out[r1*IMG + i] = 1.0f;
            out[r2*IMG + i] = 1.0f;
        }
        for (int i = r1 + lane; i <= r2; i += 64) {
            out[i*IMG + c1] = 1.0f;
            out[i*IMG + c2] = 1.0f;
        }
    }
}

extern "C" void kernel_launch(void* const* d_in, const int* in_sizes, int n_in,
                              void* d_out, int out_size, void* d_ws, size_t ws_size,
                              hipStream_t stream)
{
    const float* in      = (const float*)d_in[0];
    const float* anchors = (const float*)d_in[1];
    float* out           = (float*)d_out;

    char* ws = (char*)d_ws;
    size_t off = 0;
    float4* boxById = (float4*)(ws + off); off += (size_t)NBOX * sizeof(float4);   // 1,557,504
    u64*    allKey  = (u64*)(ws + off);    off += (size_t)NBOX * sizeof(u64);      //   778,752
    u8*     clsOf   = (u8*)(ws + off);     off += (size_t)NBOX;                    //    97,344

    decode_kernel<<<(NBOX + DB - 1)/DB, DB, 0, stream>>>(in, anchors, boxById, allKey,
                                                         clsOf, (float4*)out);
    select_draw_kernel<<<NC, 1024, 0, stream>>>(boxById, allKey, clsOf, out);
}